// Round 1
// baseline (233.349 us; speedup 1.0000x reference)
//
#include <hip/hip_runtime.h>
#include <stdint.h>
#include <stddef.h>

// Problem: B=4, C=256, CR=32, H=W=64, N=4096
#define Bn 4
#define Cn 256
#define CRn 32
#define Nn 4096

typedef __attribute__((ext_vector_type(8))) short short8v;  // 8 bf16 (4 VGPR)
typedef __attribute__((ext_vector_type(4))) float f32x4;

__device__ __forceinline__ unsigned short f2bf(float f) {
  unsigned int u = __float_as_uint(f);
  u += 0x7FFFu + ((u >> 16) & 1u);   // RNE
  return (unsigned short)(u >> 16);
}

// ---------------- kernel 1: x [B][C][N] f32 -> xT [B][N][C] bf16 ----------------
__global__ void __launch_bounds__(256) k_transpose(const float* __restrict__ x,
                                                   unsigned short* __restrict__ xT) {
  __shared__ float xs[64][65];
  const int t = threadIdx.x;
  const int n0 = blockIdx.x << 6;
  const int c0 = blockIdx.y << 6;
  const int b  = blockIdx.z;
  const int ln = t & 63, g = t >> 6;
#pragma unroll
  for (int i = 0; i < 16; ++i) {
    int c = g + (i << 2);
    xs[c][ln] = x[(((size_t)(b * Cn + c0 + c)) << 12) + n0 + ln];
  }
  __syncthreads();
#pragma unroll
  for (int i = 0; i < 16; ++i) {
    int nl = g + (i << 2);
    xT[(((size_t)((b << 12) + n0 + nl)) << 8) + c0 + ln] = f2bf(xs[ln][nl]);
  }
}

// ---------------- kernel 2: fused projections (MFMA) ----------------
// W' rows: [0..31]=Wq, [32..63]=Wk, [64..319]=Wv.  D[n][r] = sum_c xT[n][c] * W'[r][c]
// outputs: Qt [B][N][32] bf16, Kt [B][N][32] bf16, V [B][C][N] bf16
__global__ void __launch_bounds__(256) k_proj(const float* __restrict__ Wq,
                                              const float* __restrict__ Wk,
                                              const float* __restrict__ Wv,
                                              const unsigned short* __restrict__ xT,
                                              unsigned short* __restrict__ Qt,
                                              unsigned short* __restrict__ Kt,
                                              unsigned short* __restrict__ V) {
  __shared__ unsigned short Wt[64][264];  // 64 W-rows x 256 c, pad->264 (stride 528B: 2-way banks)
  const int t  = threadIdx.x;
  const int nt = blockIdx.x;   // n-tile (64 rows)
  const int rt = blockIdx.y;   // r-tile: 0 => Q+K rows, 1..4 => V rows
  const int b  = blockIdx.z;

  {  // stage W tile rows rt*64.. as bf16
    const int row = t >> 2;
    const int cb = (t & 3) << 6;
    const float* src;
    if (rt == 0) src = (row < 32) ? (Wq + row * 256) : (Wk + (row - 32) * 256);
    else         src = Wv + ((rt - 1) * 64 + row) * 256;
#pragma unroll
    for (int k = 0; k < 16; ++k) {
      float4 f = *reinterpret_cast<const float4*>(src + cb + (k << 2));
      Wt[row][cb + (k << 2) + 0] = f2bf(f.x);
      Wt[row][cb + (k << 2) + 1] = f2bf(f.y);
      Wt[row][cb + (k << 2) + 2] = f2bf(f.z);
      Wt[row][cb + (k << 2) + 3] = f2bf(f.w);
    }
  }
  __syncthreads();

  const int lane = t & 63, w = t >> 6, col = lane & 15, hi = lane >> 4;
  f32x4 zero4 = {0.f, 0.f, 0.f, 0.f};
  f32x4 acc[4];
#pragma unroll
  for (int rc = 0; rc < 4; ++rc) acc[rc] = zero4;

  // A-frag source: xT row (n), contiguous c
  const unsigned short* xrow = xT + (((size_t)((b << 12) + (nt << 6) + (w << 4) + col)) << 8);
#pragma unroll
  for (int ks = 0; ks < 8; ++ks) {
    short8v a = *reinterpret_cast<const short8v*>(xrow + (ks << 5) + (hi << 3));
#pragma unroll
    for (int rc = 0; rc < 4; ++rc) {
      short8v bf = *reinterpret_cast<const short8v*>(&Wt[(rc << 4) + col][(ks << 5) + (hi << 3)]);
      acc[rc] = __builtin_amdgcn_mfma_f32_16x16x32_bf16(a, bf, acc[rc], 0, 0, 0);
    }
  }

  if (rt == 0) {
    // D[n][o]: rc 0..1 -> Qt, rc 2..3 -> Kt  (both stored [n][32], o contiguous)
#pragma unroll
    for (int rc = 0; rc < 2; ++rc)
#pragma unroll
      for (int r = 0; r < 4; ++r) {
        int n = (nt << 6) + (w << 4) + (hi << 2) + r;
        Qt[(((size_t)((b << 12) + n)) << 5) + (rc << 4) + col] = f2bf(acc[rc][r]);
      }
#pragma unroll
    for (int rc = 2; rc < 4; ++rc)
#pragma unroll
      for (int r = 0; r < 4; ++r) {
        int n = (nt << 6) + (w << 4) + (hi << 2) + r;
        Kt[(((size_t)((b << 12) + n)) << 5) + ((rc - 2) << 4) + col] = f2bf(acc[rc][r]);
      }
  } else {
    // transpose D[n][r] -> V[c][n] via per-wave LDS buffer (reuse Wt space)
    __syncthreads();  // all waves done reading Wt
    unsigned short* tb = &Wt[0][0] + w * (64 * 24);  // [64 r][24 pad] per wave
#pragma unroll
    for (int rc = 0; rc < 4; ++rc)
#pragma unroll
      for (int r = 0; r < 4; ++r)
        tb[((rc << 4) + col) * 24 + (hi << 2) + r] = f2bf(acc[rc][r]);
    __syncthreads();
#pragma unroll
    for (int it = 0; it < 16; ++it) {
      int rl = hi + (it << 2);                    // 0..63 W-row local
      int cg = ((rt - 1) << 6) + rl;              // V channel
      int ng = (nt << 6) + (w << 4) + col;        // n
      V[(((size_t)((b << 8) + cg)) << 12) + ng] = tb[rl * 24 + col];
    }
  }
}

// ---------------- kernel 3: flash attention ----------------
// per block: 64 q-rows (one batch), 4 waves. wave w owns softmax columns n = w*16..+15
// and O^T channel slice c = w*64..+63.
// S^T = mfma(A=K, B=Q^T)  ;  O^T = mfma(A=V, B=P^T)
__global__ void __launch_bounds__(256) k_attn(const unsigned short* __restrict__ Qt,
                                              const unsigned short* __restrict__ Kt,
                                              const unsigned short* __restrict__ V,
                                              const float* __restrict__ x,
                                              float* __restrict__ out) {
  __shared__ unsigned short Qs[64][40];   // pad 40: 80B rows -> 2-way banks
  __shared__ unsigned short Ks[64][40];
  __shared__ unsigned short Vs[256 * 64]; // linear [c][64] 128B rows; XOR-swizzled content
  __shared__ unsigned short Pt[64][72];   // P^T stored [n][m], pad 72
  __shared__ float Sc[64];
  __shared__ float Ld[64];

  const int t = threadIdx.x;
  const int bx = blockIdx.x;
  // XCD swizzle: 2 XCDs per batch -> V panel (2MB) stays in a 4MB L2
  const int xcd = bx & 7, idx = bx >> 3;
  const int b  = xcd >> 1;
  const int qt = ((xcd & 1) << 5) + idx;          // 0..63
  const int lane = t & 63, w = t >> 6, col = lane & 15, hi = lane >> 4;

  // stage Q tile [64][32] -> Qs
  {
    const int mr = t >> 2, u = t & 3;
    int4 d = *reinterpret_cast<const int4*>(Qt + (((size_t)((b << 12) + (qt << 6) + mr)) << 5) + (u << 3));
    *reinterpret_cast<int4*>(&Qs[mr][u << 3]) = d;
  }
  __syncthreads();
  const short8v qf = *reinterpret_cast<const short8v*>(&Qs[(w << 4) + col][hi << 3]);

  f32x4 zero4 = {0.f, 0.f, 0.f, 0.f};
  f32x4 o_acc[4][4];
#pragma unroll
  for (int cb = 0; cb < 4; ++cb)
#pragma unroll
    for (int nc = 0; nc < 4; ++nc) o_acc[cb][nc] = zero4;
  float m_run = -3e38f, l_run = 0.f;

  for (int kt = 0; kt < 64; ++kt) {
    const int m0 = kt << 6;
    {  // stage K tile [64][32] -> Ks (reg-staged, coalesced 1KB/wave)
      const int mr = t >> 2, u = t & 3;
      int4 d = *reinterpret_cast<const int4*>(Kt + (((size_t)((b << 12) + m0 + mr)) << 5) + (u << 3));
      *reinterpret_cast<int4*>(&Ks[mr][u << 3]) = d;
    }
    // stage V tile [256 c][64 m] via global_load_lds; linear LDS dest, pre-swizzled source.
    // LDS[c][u] (16B units) = global V[c][m0 + 8*(u ^ (c&7))]
#pragma unroll
    for (int s = 0; s < 8; ++s) {
      int crow = (w << 6) + (s << 3) + (lane >> 3);
      int usrc = (lane & 7) ^ (lane >> 3);
      const unsigned short* g = V + (((size_t)((b << 8) + crow)) << 12) + m0 + (usrc << 3);
      __builtin_amdgcn_global_load_lds(
          (const __attribute__((address_space(1))) void*)g,
          (__attribute__((address_space(3))) void*)(&Vs[((w << 6) + (s << 3)) << 6]),
          16, 0, 0);
    }
    __syncthreads();  // drains vmcnt (gload_lds) + lgkm (ds_write)

    // ---- S^T slice: rows m (4 chunks), cols n = w*16..+15 ----
    f32x4 s_acc[4];
#pragma unroll
    for (int mb = 0; mb < 4; ++mb) {
      short8v a = *reinterpret_cast<const short8v*>(&Ks[(mb << 4) + col][hi << 3]);
      s_acc[mb] = __builtin_amdgcn_mfma_f32_16x16x32_bf16(a, qf, zero4, 0, 0, 0);
    }
    // ---- wave-local online softmax for column n = qt*64 + w*16 + col ----
    float tm = -3e38f;
#pragma unroll
    for (int mb = 0; mb < 4; ++mb)
#pragma unroll
      for (int r = 0; r < 4; ++r) tm = fmaxf(tm, s_acc[mb][r]);
    tm = fmaxf(tm, __shfl_xor(tm, 16));
    tm = fmaxf(tm, __shfl_xor(tm, 32));
    float mn = fmaxf(m_run, tm);
    float sc = __expf(m_run - mn);
    m_run = mn;
    float ps = 0.f;
#pragma unroll
    for (int mb = 0; mb < 4; ++mb)
#pragma unroll
      for (int r = 0; r < 4; ++r) {
        float p = __expf(s_acc[mb][r] - mn);
        s_acc[mb][r] = p;
        ps += p;
      }
    ps += __shfl_xor(ps, 16);
    ps += __shfl_xor(ps, 32);
    l_run = l_run * sc + ps;
    if (hi == 0) Sc[(w << 4) + col] = sc;
    // write P^T bf16: Pt[n-local][m-local]
#pragma unroll
    for (int mb = 0; mb < 4; ++mb)
#pragma unroll
      for (int r = 0; r < 4; ++r)
        Pt[(w << 4) + col][(mb << 4) + (hi << 2) + r] = f2bf(s_acc[mb][r]);
    __syncthreads();

    // ---- rescale O^T, then PV: O^T[c][n] += V[c][m] * P^T[m][n] ----
    float scl[4];
#pragma unroll
    for (int nc = 0; nc < 4; ++nc) scl[nc] = Sc[(nc << 4) + col];
#pragma unroll
    for (int cb = 0; cb < 4; ++cb)
#pragma unroll
      for (int nc = 0; nc < 4; ++nc) o_acc[cb][nc] *= scl[nc];

#pragma unroll
    for (int ks = 0; ks < 2; ++ks) {
      short8v pb[4];
#pragma unroll
      for (int nc = 0; nc < 4; ++nc)
        pb[nc] = *reinterpret_cast<const short8v*>(&Pt[(nc << 4) + col][(ks << 5) + (hi << 3)]);
#pragma unroll
      for (int cb = 0; cb < 4; ++cb) {
        int crow = (w << 6) + (cb << 4) + col;
        int uu = ((ks << 2) + hi) ^ (col & 7);  // un-swizzle
        short8v va = *reinterpret_cast<const short8v*>(&Vs[(crow << 6) + (uu << 3)]);
#pragma unroll
        for (int nc = 0; nc < 4; ++nc)
          o_acc[cb][nc] = __builtin_amdgcn_mfma_f32_16x16x32_bf16(va, pb[nc], o_acc[cb][nc], 0, 0, 0);
      }
    }
    __syncthreads();  // protect Ks/Vs/Pt/Sc before next stage
  }

  // ---- epilogue: out[b][c][n] = O^T[c][n]/l_n + x[b][c][n] ----
  if (hi == 0) Ld[(w << 4) + col] = l_run;
  __syncthreads();
  float linv[4];
#pragma unroll
  for (int nc = 0; nc < 4; ++nc) linv[nc] = 1.f / Ld[(nc << 4) + col];
#pragma unroll
  for (int cb = 0; cb < 4; ++cb)
#pragma unroll
    for (int nc = 0; nc < 4; ++nc)
#pragma unroll
      for (int r = 0; r < 4; ++r) {
        int cg = (w << 6) + (cb << 4) + (hi << 2) + r;
        int ng = (qt << 6) + (nc << 4) + col;
        size_t off = (((size_t)((b << 8) + cg)) << 12) + ng;
        out[off] = o_acc[cb][nc][r] * linv[nc] + x[off];
      }
}

// ---------------- launcher ----------------
extern "C" void kernel_launch(void* const* d_in, const int* in_sizes, int n_in,
                              void* d_out, int out_size, void* d_ws, size_t ws_size,
                              hipStream_t stream) {
  (void)in_sizes; (void)n_in; (void)out_size; (void)ws_size;
  const float* x  = (const float*)d_in[0];
  const float* Wq = (const float*)d_in[1];
  const float* Wk = (const float*)d_in[2];
  const float* Wv = (const float*)d_in[3];
  float* out = (float*)d_out;

  unsigned short* xT = (unsigned short*)d_ws;                      // [B][N][C]   8.39 MB
  unsigned short* Qt = xT + (size_t)Bn * Nn * Cn;                  // [B][N][32]  1.05 MB
  unsigned short* Kt = Qt + (size_t)Bn * Nn * CRn;                 // [B][N][32]  1.05 MB
  unsigned short* Vv = Kt + (size_t)Bn * Nn * CRn;                 // [B][C][N]   8.39 MB
  // total ws: ~18.9 MB

  hipLaunchKernelGGL(k_transpose, dim3(64, 4, 4), dim3(256), 0, stream, x, xT);
  hipLaunchKernelGGL(k_proj,      dim3(64, 5, 4), dim3(256), 0, stream, Wq, Wk, Wv, xT, Qt, Kt, Vv);
  hipLaunchKernelGGL(k_attn,      dim3(256),      dim3(256), 0, stream, Qt, Kt, Vv, x, out);
}

// Round 4
// 185.801 us; speedup vs baseline: 1.2559x; 1.2559x over previous
//
#include <hip/hip_runtime.h>
#include <stdint.h>
#include <stddef.h>

// Problem: B=4, C=256, CR=32, H=W=64, N=4096
#define Bn 4
#define Cn 256
#define CRn 32
#define Nn 4096

typedef __attribute__((ext_vector_type(8))) short short8v;  // 8 bf16 (4 VGPR)
typedef __attribute__((ext_vector_type(4))) float f32x4;

__device__ __forceinline__ unsigned short f2bf(float f) {
  unsigned int u = __float_as_uint(f);
  u += 0x7FFFu + ((u >> 16) & 1u);   // RNE
  return (unsigned short)(u >> 16);
}

// ---------------- kernel 0: cast W (Wq|Wk|Wv rows) -> Wb [320][256] bf16 ----------------
__global__ void __launch_bounds__(256) k_wcast(const float* __restrict__ Wq,
                                               const float* __restrict__ Wk,
                                               const float* __restrict__ Wv,
                                               unsigned short* __restrict__ Wb) {
  int idx = (blockIdx.x * 256 + threadIdx.x) * 4;   // 80 blocks -> 81920 elems
  int row = idx >> 8, cc = idx & 255;
  const float* src = (row < 32) ? &Wq[row * 256 + cc]
                   : (row < 64) ? &Wk[(row - 32) * 256 + cc]
                                : &Wv[(row - 64) * 256 + cc];
  float4 f = *reinterpret_cast<const float4*>(src);
  ushort4 o;
  o.x = f2bf(f.x); o.y = f2bf(f.y); o.z = f2bf(f.z); o.w = f2bf(f.w);
  *reinterpret_cast<ushort4*>(&Wb[idx]) = o;
}

// ---------------- kernel 1: x [B][C][N] f32 -> xT [B][N][C] bf16 ----------------
__global__ void __launch_bounds__(256) k_transpose(const float* __restrict__ x,
                                                   unsigned short* __restrict__ xT) {
  __shared__ float xs[64][65];
  const int t = threadIdx.x;
  const int n0 = blockIdx.x << 6;
  const int c0 = blockIdx.y << 6;
  const int b  = blockIdx.z;
  const int li = t & 15, g4 = t >> 4;
#pragma unroll
  for (int it = 0; it < 4; ++it) {
    int c = g4 + (it << 4);
    float4 f = *reinterpret_cast<const float4*>(
        &x[(((size_t)(b * Cn + c0 + c)) << 12) + n0 + (li << 2)]);
    xs[c][(li << 2) + 0] = f.x;
    xs[c][(li << 2) + 1] = f.y;
    xs[c][(li << 2) + 2] = f.z;
    xs[c][(li << 2) + 3] = f.w;
  }
  __syncthreads();
#pragma unroll
  for (int it = 0; it < 4; ++it) {
    int nl = g4 + (it << 4);
    int cq = li << 2;
    ushort4 o;
    o.x = f2bf(xs[cq + 0][nl]);
    o.y = f2bf(xs[cq + 1][nl]);
    o.z = f2bf(xs[cq + 2][nl]);
    o.w = f2bf(xs[cq + 3][nl]);
    *reinterpret_cast<ushort4*>(&xT[(((size_t)((b << 12) + n0 + nl)) << 8) + c0 + cq]) = o;
  }
}

// ---------------- kernel 2: fused projections (MFMA, no LDS staging) ----------------
// Wb rows: [0..31]=Wq, [32..63]=Wk, [64..319]=Wv.  D[n][r] = sum_c xT[n][c] * Wb[r][c]
__global__ void __launch_bounds__(256) k_proj(const unsigned short* __restrict__ Wb,
                                              const unsigned short* __restrict__ xT,
                                              unsigned short* __restrict__ Qt,
                                              unsigned short* __restrict__ Kt,
                                              unsigned short* __restrict__ V) {
  __shared__ unsigned short tb[4][64 * 24];   // per-wave transpose buffer (V path)
  const int t  = threadIdx.x;
  const int nt = blockIdx.x;   // n-tile (64 rows)
  const int rt = blockIdx.y;   // 0 => Q+K rows (Wb 0..63), 1..4 => V rows (Wb 64..319)
  const int b  = blockIdx.z;
  const int lane = t & 63, w = t >> 6, col = lane & 15, hi = lane >> 4;

  f32x4 zero4 = {0.f, 0.f, 0.f, 0.f};
  f32x4 acc[4];
#pragma unroll
  for (int rc = 0; rc < 4; ++rc) acc[rc] = zero4;

  const unsigned short* xrow = xT + (((size_t)((b << 12) + (nt << 6) + (w << 4) + col)) << 8);
#pragma unroll
  for (int ks = 0; ks < 8; ++ks) {
    short8v a = *reinterpret_cast<const short8v*>(xrow + (ks << 5) + (hi << 3));
#pragma unroll
    for (int rc = 0; rc < 4; ++rc) {
      short8v bf = *reinterpret_cast<const short8v*>(
          Wb + (((size_t)((rt << 6) + (rc << 4) + col)) << 8) + (ks << 5) + (hi << 3));
      acc[rc] = __builtin_amdgcn_mfma_f32_16x16x32_bf16(a, bf, acc[rc], 0, 0, 0);
    }
  }

  if (rt == 0) {
#pragma unroll
    for (int rc = 0; rc < 2; ++rc)
#pragma unroll
      for (int r = 0; r < 4; ++r) {
        int n = (nt << 6) + (w << 4) + (hi << 2) + r;
        Qt[(((size_t)((b << 12) + n)) << 5) + (rc << 4) + col] = f2bf(acc[rc][r]);
      }
#pragma unroll
    for (int rc = 2; rc < 4; ++rc)
#pragma unroll
      for (int r = 0; r < 4; ++r) {
        int n = (nt << 6) + (w << 4) + (hi << 2) + r;
        Kt[(((size_t)((b << 12) + n)) << 5) + ((rc - 2) << 4) + col] = f2bf(acc[rc][r]);
      }
  } else {
    unsigned short* tbw = &tb[w][0];
#pragma unroll
    for (int rc = 0; rc < 4; ++rc)
#pragma unroll
      for (int r = 0; r < 4; ++r)
        tbw[((rc << 4) + col) * 24 + (hi << 2) + r] = f2bf(acc[rc][r]);
    __syncthreads();
#pragma unroll
    for (int it = 0; it < 16; ++it) {
      int rl = hi + (it << 2);
      int cg = ((rt - 1) << 6) + rl;
      int ng = (nt << 6) + (w << 4) + col;
      V[(((size_t)((b << 8) + cg)) << 12) + ng] = tbw[rl * 24 + col];
    }
  }
}

// ---------------- kernel 3: flash attention, 8 waves, KV-split ----------------
// group g = w>>2 handles kt in [g*32, g*32+32); wave-in-group wg = w&3 owns
// softmax cols n = wg*16..+15 and O^T channel slice c = wg*64..+63.
// S^T = mfma(A=K, B=Q^T) ; O^T = mfma(A=V(direct-from-L2 regs), B=P^T)
__global__ void __launch_bounds__(512, 2) k_attn(const unsigned short* __restrict__ Qt,
                                                 const unsigned short* __restrict__ Kt,
                                                 const unsigned short* __restrict__ Vv,
                                                 const float* __restrict__ x,
                                                 float* __restrict__ out) {
  __shared__ unsigned short Qs[64][40];
  __shared__ unsigned short Ks[2][64][40];
  __shared__ __align__(16) unsigned short Pt[2][64 * 64];  // linear, 16B-unit XOR swizzle
  __shared__ float Sc[2][64];
  __shared__ float Mm[2][64], Ll[2][64];
  __shared__ float Ob[4][16][64];

  const int t = threadIdx.x;
  const int bx = blockIdx.x;
  // XCD swizzle: 2 XCDs per batch -> V panel (2MB bf16) stays in a 4MB L2
  const int xcd = bx & 7, idx = bx >> 3;
  const int b  = xcd >> 1;
  const int qt = ((xcd & 1) << 5) + idx;          // 0..63
  const int lane = t & 63, w = t >> 6, col = lane & 15, hi = lane >> 4;
  const int g = w >> 2, wg = w & 3;
  const int tl = t & 255;

  if (t < 256) {  // stage Q tile [64][32]
    const int mr = t >> 2, u = t & 3;
    int4 d = *reinterpret_cast<const int4*>(
        Qt + (((size_t)((b << 12) + (qt << 6) + mr)) << 5) + (u << 3));
    *reinterpret_cast<int4*>(&Qs[mr][u << 3]) = d;
  }

  const int kt0 = g << 5;
  int4 kregA, kregB;
  kregA = *reinterpret_cast<const int4*>(
      Kt + (((size_t)((b << 12) + (kt0 << 6) + (tl >> 2))) << 5) + ((tl & 3) << 3));
  short8v vaA[8], vaB[8];
#pragma unroll
  for (int ks = 0; ks < 2; ++ks)
#pragma unroll
    for (int cb = 0; cb < 4; ++cb)
      vaA[(ks << 2) + cb] = *reinterpret_cast<const short8v*>(
          Vv + (((size_t)((b << 8) + (wg << 6) + (cb << 4) + col)) << 12)
             + (kt0 << 6) + (ks << 5) + (hi << 3));
  __syncthreads();
  const short8v qf = *reinterpret_cast<const short8v*>(&Qs[(wg << 4) + col][hi << 3]);

  f32x4 zero4 = {0.f, 0.f, 0.f, 0.f};
  f32x4 o_acc[4][4];
#pragma unroll
  for (int cb = 0; cb < 4; ++cb)
#pragma unroll
    for (int nc = 0; nc < 4; ++nc) o_acc[cb][nc] = zero4;
  float m_run = -3e38f, l_run = 0.f;

#define PHASE(curV, nxtV, curK, nxtK, KT)                                            \
  {                                                                                  \
    *reinterpret_cast<int4*>(&Ks[g][tl >> 2][(tl & 3) << 3]) = curK;                 \
    int ktn = (KT) + 1; if (ktn > 63) ktn = 63;                                      \
    nxtK = *reinterpret_cast<const int4*>(                                           \
        Kt + (((size_t)((b << 12) + (ktn << 6) + (tl >> 2))) << 5) + ((tl & 3) << 3)); \
    __syncthreads();                                                                 \
    f32x4 s_acc[4];                                                                  \
    _Pragma("unroll")                                                                \
    for (int mb = 0; mb < 4; ++mb) {                                                 \
      short8v af = *reinterpret_cast<const short8v*>(&Ks[g][(mb << 4) + col][hi << 3]); \
      s_acc[mb] = __builtin_amdgcn_mfma_f32_16x16x32_bf16(af, qf, zero4, 0, 0, 0);   \
    }                                                                                \
    float tm = -3e38f;                                                               \
    _Pragma("unroll")                                                                \
    for (int mb = 0; mb < 4; ++mb)                                                   \
      _Pragma("unroll")                                                              \
      for (int r = 0; r < 4; ++r) tm = fmaxf(tm, s_acc[mb][r]);                      \
    tm = fmaxf(tm, __shfl_xor(tm, 16));                                              \
    tm = fmaxf(tm, __shfl_xor(tm, 32));                                              \
    float mn = fmaxf(m_run, tm);                                                     \
    float sc = __expf(m_run - mn);                                                   \
    m_run = mn;                                                                      \
    float ps = 0.f;                                                                  \
    _Pragma("unroll")                                                                \
    for (int mb = 0; mb < 4; ++mb)                                                   \
      _Pragma("unroll")                                                              \
      for (int r = 0; r < 4; ++r) {                                                  \
        float p = __expf(s_acc[mb][r] - mn);                                         \
        s_acc[mb][r] = p;                                                            \
        ps += p;                                                                     \
      }                                                                              \
    ps += __shfl_xor(ps, 16);                                                        \
    ps += __shfl_xor(ps, 32);                                                        \
    l_run = l_run * sc + ps;                                                         \
    if (hi == 0) Sc[g][(wg << 4) + col] = sc;                                        \
    _Pragma("unroll")                                                                \
    for (int mb = 0; mb < 4; ++mb) {                                                 \
      uint2 pk2;                                                                     \
      pk2.x = (unsigned)f2bf(s_acc[mb][0]) | ((unsigned)f2bf(s_acc[mb][1]) << 16);   \
      pk2.y = (unsigned)f2bf(s_acc[mb][2]) | ((unsigned)f2bf(s_acc[mb][3]) << 16);   \
      int uu = (mb << 1) + (hi >> 1);                                                \
      int up = uu ^ (col & 7);                                                       \
      *reinterpret_cast<uint2*>(                                                     \
          &Pt[g][(((wg << 4) + col) << 6) + (up << 3) + ((hi & 1) << 2)]) = pk2;     \
    }                                                                                \
    {                                                                                \
      int m0n = ktn << 6;                                                            \
      _Pragma("unroll")                                                              \
      for (int ks = 0; ks < 2; ++ks)                                                 \
        _Pragma("unroll")                                                            \
        for (int cb = 0; cb < 4; ++cb)                                               \
          nxtV[(ks << 2) + cb] = *reinterpret_cast<const short8v*>(                  \
              Vv + (((size_t)((b << 8) + (wg << 6) + (cb << 4) + col)) << 12)        \
                 + m0n + (ks << 5) + (hi << 3));                                     \
    }                                                                                \
    __syncthreads();                                                                 \
    float scl[4];                                                                    \
    _Pragma("unroll")                                                                \
    for (int nc = 0; nc < 4; ++nc) scl[nc] = Sc[g][(nc << 4) + col];                 \
    _Pragma("unroll")                                                                \
    for (int cb = 0; cb < 4; ++cb)                                                   \
      _Pragma("unroll")                                                              \
      for (int nc = 0; nc < 4; ++nc) o_acc[cb][nc] *= scl[nc];                       \
    _Pragma("unroll")                                                                \
    for (int ks = 0; ks < 2; ++ks) {                                                 \
      short8v pb[4];                                                                 \
      int up2 = ((ks << 2) + hi) ^ (col & 7);                                        \
      _Pragma("unroll")                                                              \
      for (int nc = 0; nc < 4; ++nc)                                                 \
        pb[nc] = *reinterpret_cast<const short8v*>(                                  \
            &Pt[g][(((nc << 4) + col) << 6) + (up2 << 3)]);                          \
      _Pragma("unroll")                                                              \
      for (int cb = 0; cb < 4; ++cb) {                                               \
        _Pragma("unroll")                                                            \
        for (int nc = 0; nc < 4; ++nc)                                               \
          o_acc[cb][nc] = __builtin_amdgcn_mfma_f32_16x16x32_bf16(                   \
              curV[(ks << 2) + cb], pb[nc], o_acc[cb][nc], 0, 0, 0);                 \
      }                                                                              \
    }                                                                                \
  }

#pragma unroll 1
  for (int i2 = 0; i2 < 16; ++i2) {
    PHASE(vaA, vaB, kregA, kregB, kt0 + (i2 << 1));
    PHASE(vaB, vaA, kregB, kregA, kt0 + (i2 << 1) + 1);
  }
#undef PHASE

  // ---- merge the two KV-groups + epilogue ----
  if (hi == 0) { Mm[g][(wg << 4) + col] = m_run; Ll[g][(wg << 4) + col] = l_run; }
  __syncthreads();
  float fa[4], fb[4], linv[4];
#pragma unroll
  for (int nc = 0; nc < 4; ++nc) {
    float ma = Mm[0][(nc << 4) + col], mb2 = Mm[1][(nc << 4) + col];
    float mm = fmaxf(ma, mb2);
    float ea = __expf(ma - mm), eb = __expf(mb2 - mm);
    linv[nc] = 1.f / (Ll[0][(nc << 4) + col] * ea + Ll[1][(nc << 4) + col] * eb);
    fa[nc] = ea; fb[nc] = eb;
  }
#pragma unroll
  for (int cb = 0; cb < 4; ++cb) {
    if (g == 1) {
#pragma unroll
      for (int nc = 0; nc < 4; ++nc)
#pragma unroll
        for (int r = 0; r < 4; ++r)
          Ob[wg][(nc << 2) + r][lane] = o_acc[cb][nc][r];
    }
    __syncthreads();
    if (g == 0) {
#pragma unroll
      for (int nc = 0; nc < 4; ++nc)
#pragma unroll
        for (int r = 0; r < 4; ++r) {
          float o = o_acc[cb][nc][r] * fa[nc] + Ob[wg][(nc << 2) + r][lane] * fb[nc];
          int cg = (wg << 6) + (cb << 4) + (hi << 2) + r;
          int ng = (qt << 6) + (nc << 4) + col;
          size_t off = (((size_t)((b << 8) + cg)) << 12) + ng;
          out[off] = o * linv[nc] + x[off];
        }
    }
    __syncthreads();
  }
}

// ---------------- launcher ----------------
extern "C" void kernel_launch(void* const* d_in, const int* in_sizes, int n_in,
                              void* d_out, int out_size, void* d_ws, size_t ws_size,
                              hipStream_t stream) {
  (void)in_sizes; (void)n_in; (void)out_size; (void)ws_size;
  const float* x  = (const float*)d_in[0];
  const float* Wq = (const float*)d_in[1];
  const float* Wk = (const float*)d_in[2];
  const float* Wv = (const float*)d_in[3];
  float* out = (float*)d_out;

  unsigned short* xT = (unsigned short*)d_ws;                      // [B][N][C]   8.39 MB
  unsigned short* Qt = xT + (size_t)Bn * Nn * Cn;                  // [B][N][32]  1.05 MB
  unsigned short* Kt = Qt + (size_t)Bn * Nn * CRn;                 // [B][N][32]  1.05 MB
  unsigned short* Vv = Kt + (size_t)Bn * Nn * CRn;                 // [B][C][N]   8.39 MB
  unsigned short* Wb = Vv + (size_t)Bn * Cn * Nn;                  // [320][256]  164 KB

  hipLaunchKernelGGL(k_wcast,     dim3(80),        dim3(256), 0, stream, Wq, Wk, Wv, Wb);
  hipLaunchKernelGGL(k_transpose, dim3(64, 4, 4),  dim3(256), 0, stream, x, xT);
  hipLaunchKernelGGL(k_proj,      dim3(64, 5, 4),  dim3(256), 0, stream, Wb, xT, Qt, Kt, Vv);
  hipLaunchKernelGGL(k_attn,      dim3(256),       dim3(512), 0, stream, Qt, Kt, Vv, x, out);
}